// Round 1
// baseline (515.557 us; speedup 1.0000x reference)
//
#include <hip/hip_runtime.h>

namespace {

constexpr int B = 64;
constexpr int N = 64;
constexpr int D = 64;
constexpr int E = 2 * D + 1;  // 129

// One block per (i,j) pair; early-exit if not an edge.
// Computes msg[b,i,j,:] for all b and atomically accumulates into agg[b,i,:].
__global__ __launch_bounds__(256) void k_msg(
    const float* __restrict__ s,     // [B][N][D]
    const float* __restrict__ ew,    // [N][N]
    const float* __restrict__ Wm,    // [N][N][E][D]  (layer slice)
    const float* __restrict__ bm,    // [N][N][D]     (layer slice)
    float* __restrict__ agg)         // [B][N][D]
{
  const int ij = blockIdx.x;
  const int i = ij >> 6;
  const int j = ij & 63;
  const float w = ew[ij];
  if (w == 0.0f) return;  // uniform across block

  __shared__ float siT[D][B];  // siT[k][b] = s[b][i][k]
  __shared__ float sjT[D][B];

  const int t = threadIdx.x;
  {
    const int bb = t >> 2;   // 0..63
    const int q  = t & 3;    // 0..3
    const float* ps = s + ((size_t)bb * N + i) * D;
    const float* pq = s + ((size_t)bb * N + j) * D;
#pragma unroll
    for (int kc = 0; kc < 4; ++kc) {
      const int k0 = kc * 16 + q * 4;
      float4 v = *(const float4*)(ps + k0);
      siT[k0 + 0][bb] = v.x;
      siT[k0 + 1][bb] = v.y;
      siT[k0 + 2][bb] = v.z;
      siT[k0 + 3][bb] = v.w;
      float4 u2 = *(const float4*)(pq + k0);
      sjT[k0 + 0][bb] = u2.x;
      sjT[k0 + 1][bb] = u2.y;
      sjT[k0 + 2][bb] = u2.z;
      sjT[k0 + 3][bb] = u2.w;
    }
  }
  __syncthreads();

  const int b  = t & 63;                                    // lane = batch
  const int d0 = __builtin_amdgcn_readfirstlane(t >> 6) * 16;  // wave-uniform d-chunk
  const float* __restrict__ Wp = Wm + (size_t)ij * (E * D);
  const float* __restrict__ bp = bm + (size_t)ij * D;

  float acc[16];
#pragma unroll
  for (int u = 0; u < 16; ++u)
    acc[u] = w * Wp[128 * D + d0 + u] + bp[d0 + u];  // e = 2D term + bias

  for (int k = 0; k < D; ++k) {
    const float a  = siT[k][b];
    const float c2 = sjT[k][b];
    const float* __restrict__ w1 = Wp + (size_t)k * D + d0;        // feat_i part
    const float* __restrict__ w2 = Wp + (size_t)(D + k) * D + d0;  // feat_j part
#pragma unroll
    for (int u = 0; u < 16; ++u)
      acc[u] += a * w1[u] + c2 * w2[u];
  }

  float* ap = agg + ((size_t)b * N + i) * D + d0;
#pragma unroll
  for (int u = 0; u < 16; ++u)
    atomicAdd(ap + u, acc[u]);
}

// One block per batch b: update MLP + residual mix, then the sequential
// node-smoothing scan fully in LDS (lane d owns column d -> no cross-lane deps).
__global__ __launch_bounds__(256) void k_upd_scan(
    float* __restrict__ s,          // [B][N][D] in/out
    const float* __restrict__ agg,  // [B][N][D]
    const float* __restrict__ ew,   // [N][N]
    const float* __restrict__ Wu,   // [2D][D] (layer slice)
    const float* __restrict__ bu)   // [D]     (layer slice)
{
  const int b = blockIdx.x;
  const int t = threadIdx.x;

  __shared__ float catT[2 * D][N];   // catT[k][i]: k<D -> s, k>=D -> agg (32 KB)
  __shared__ float sb[N][D + 1];     // padded: scan state
  __shared__ float degf[N];
  __shared__ int   cnt[N];
  __shared__ unsigned char nbr[N][64];

  {
    const int ii = t >> 2;
    const int q  = t & 3;
    const float* ps = s   + ((size_t)b * N + ii) * D;
    const float* pa = agg + ((size_t)b * N + ii) * D;
#pragma unroll
    for (int kc = 0; kc < 4; ++kc) {
      const int k0 = kc * 16 + q * 4;
      float4 v = *(const float4*)(ps + k0);
      catT[k0 + 0][ii] = v.x;
      catT[k0 + 1][ii] = v.y;
      catT[k0 + 2][ii] = v.z;
      catT[k0 + 3][ii] = v.w;
      float4 u2 = *(const float4*)(pa + k0);
      catT[D + k0 + 0][ii] = u2.x;
      catT[D + k0 + 1][ii] = u2.y;
      catT[D + k0 + 2][ii] = u2.z;
      catT[D + k0 + 3][ii] = u2.w;
    }
  }
  if (t < N) {
    int c = 0;
    for (int jj = 0; jj < N; ++jj)
      if (ew[t * N + jj] > 0.0f) nbr[t][c++] = (unsigned char)jj;
    cnt[t]  = c;
    degf[t] = (float)c;
  }
  __syncthreads();

  // upd GEMM: out[i][d] = cat[i][:] . Wu[:][d] ; lane = i, wave-uniform d-chunk
  const int i  = t & 63;
  const int d0 = __builtin_amdgcn_readfirstlane(t >> 6) * 16;

  float acc[16];
#pragma unroll
  for (int u = 0; u < 16; ++u) acc[u] = bu[d0 + u];

  for (int k = 0; k < 2 * D; ++k) {
    const float a = catT[k][i];
    const float* __restrict__ wr = Wu + (size_t)k * D + d0;
#pragma unroll
    for (int u = 0; u < 16; ++u) acc[u] += a * wr[u];
  }
#pragma unroll
  for (int u = 0; u < 16; ++u) {
    const float sold = catT[d0 + u][i];     // s_old[i][d0+u]
    sb[i][d0 + u] = 0.9f * acc[u] + 0.1f * sold;
  }
  __syncthreads();

  // sequential scan over nodes; lane d owns column d of sb
  if (t < N) {
    const int d = t;
    for (int ii = 0; ii < N; ++ii) {
      const int c = cnt[ii];
      float nb = 0.0f;
      for (int q = 0; q < c; ++q) nb += sb[nbr[ii][q]][d];
      const float dg  = degf[ii];
      const float avg = nb / fmaxf(dg, 1.0f);
      const float cur = sb[ii][d];
      sb[ii][d] = (dg > 0.0f) ? (0.95f * cur + 0.05f * avg) : cur;
    }
  }
  __syncthreads();

  {
    const int ii = t >> 2;
    const int q  = t & 3;
    float* ps = s + ((size_t)b * N + ii) * D;
#pragma unroll
    for (int kc = 0; kc < 4; ++kc) {
      const int k0 = kc * 16 + q * 4;
      float4 v;
      v.x = sb[ii][k0 + 0];
      v.y = sb[ii][k0 + 1];
      v.z = sb[ii][k0 + 2];
      v.w = sb[ii][k0 + 3];
      *(float4*)(ps + k0) = v;
    }
  }
}

// One block per batch b, 64 threads: readout + output projection.
__global__ __launch_bounds__(64) void k_out(
    const float* __restrict__ s,    // [B][N][D]
    const float* __restrict__ ew,   // [N][N]
    const float* __restrict__ Wo,   // [D][D]
    const float* __restrict__ bo,   // [D]
    float* __restrict__ out)        // [B][D]
{
  const int b = blockIdx.x;
  const int t = threadIdx.x;  // 0..63
  __shared__ float cl[N];
  __shared__ float gl[D];

  float ci = 0.0f;
  for (int j = 0; j < N; ++j) ci += ew[t * N + j];
  float tot = ci;
#pragma unroll
  for (int off = 32; off >= 1; off >>= 1) tot += __shfl_xor(tot, off, 64);
  cl[t] = ci / (tot + 1e-8f);
  __syncthreads();

  float g = 0.0f;
  for (int i2 = 0; i2 < N; ++i2)
    g += cl[i2] * s[((size_t)b * N + i2) * D + t];
  gl[t] = g;
  __syncthreads();

  float o = bo[t];
  for (int d = 0; d < D; ++d) o += gl[d] * Wo[d * D + t];
  out[b * D + t] = o;
}

}  // namespace

extern "C" void kernel_launch(void* const* d_in, const int* in_sizes, int n_in,
                              void* d_out, int out_size, void* d_ws, size_t ws_size,
                              hipStream_t stream)
{
  const float* x  = (const float*)d_in[0];
  const float* ew = (const float*)d_in[1];
  const float* Wm = (const float*)d_in[2];
  const float* bm = (const float*)d_in[3];
  const float* Wu = (const float*)d_in[4];
  const float* bu = (const float*)d_in[5];
  const float* Wo = (const float*)d_in[6];
  const float* bo = (const float*)d_in[7];
  float* out = (float*)d_out;

  float* s   = (float*)d_ws;
  float* agg = s + (size_t)B * N * D;

  const int L = in_sizes[2] / (N * N * E * D);  // = 3

  hipMemcpyAsync(s, x, (size_t)B * N * D * sizeof(float),
                 hipMemcpyDeviceToDevice, stream);

  for (int l = 0; l < L; ++l) {
    hipMemsetAsync(agg, 0, (size_t)B * N * D * sizeof(float), stream);
    k_msg<<<N * N, 256, 0, stream>>>(
        s, ew,
        Wm + (size_t)l * N * N * E * D,
        bm + (size_t)l * N * N * D,
        agg);
    k_upd_scan<<<B, 256, 0, stream>>>(
        s, agg, ew,
        Wu + (size_t)l * 2 * D * D,
        bu + (size_t)l * D);
  }
  k_out<<<B, 64, 0, stream>>>(s, ew, Wo, bo, out);
}